// Round 18
// baseline (461.501 us; speedup 1.0000x reference)
//
#include <hip/hip_runtime.h>
#include <cstdint>

#define NA 65536
#define NB 262144
#define MAXNB 6
#define H 256
#define BF 147
#define AF 133
#define NM 2048

typedef unsigned int u32;
typedef __attribute__((ext_vector_type(8))) short bf16x8;
typedef __attribute__((ext_vector_type(4))) float f32x4;

// bf16 helpers (manual, RNE)
__device__ __forceinline__ u32 pack_bf2(float a, float b) {
    u32 ua = __float_as_uint(a); ua = (ua + 0x7FFFu + ((ua >> 16) & 1u)) >> 16;
    u32 ub = __float_as_uint(b); ub = (ub + 0x7FFFu + ((ub >> 16) & 1u)) >> 16;
    return ua | (ub << 16);
}
__device__ __forceinline__ unsigned short bf1(float a) {
    u32 ua = __float_as_uint(a); return (unsigned short)((ua + 0x7FFFu + ((ua >> 16) & 1u)) >> 16);
}
__device__ __forceinline__ float bf_lo(u32 u) { return __uint_as_float(u << 16); }
__device__ __forceinline__ float bf_hi(u32 u) { return __uint_as_float(u & 0xFFFF0000u); }

// transpose-region swizzle (row stride 512B regions)
__device__ __forceinline__ int tswz(int row, int col) {
    int chunk = (col >> 3) ^ (((row >> 2) & 3) << 1);
    return row * 512 + (chunk << 4) + ((col & 7) << 1);
}

// ---------------------------------------------------------------------------
// K0: generic weight pack W[K][256] fp32 -> bf16 fragment layout (zero-pad K).
// ---------------------------------------------------------------------------
__global__ __launch_bounds__(256) void k_pack_w(const float* __restrict__ W,
                                                uint4* __restrict__ Wp, int K) {
    int t = blockIdx.x * 256 + threadIdx.x;
    int kbg = t >> 8, col = t & 255;
    int k0 = kbg * 8;
    float x[8];
#pragma unroll
    for (int j = 0; j < 8; ++j)
        x[j] = (k0 + j < K) ? W[(size_t)(k0 + j) * 256 + col] : 0.f;
    uint4 o;
    o.x = pack_bf2(x[0], x[1]); o.y = pack_bf2(x[2], x[3]);
    o.z = pack_bf2(x[4], x[5]); o.w = pack_bf2(x[6], x[7]);
    Wp[t] = o;
}

// ---------------------------------------------------------------------------
// K0c: W_a pack with 3-col shift (amsg block starts at padded col 136).
// ---------------------------------------------------------------------------
__global__ __launch_bounds__(256) void k_pack_wa(const float* __restrict__ W,
                                                 uint4* __restrict__ Wp) {
    int t = blockIdx.x * 256 + threadIdx.x;
    int kbg = t >> 8, col = t & 255;
    int k0 = kbg * 8;
    float x[8];
#pragma unroll
    for (int j = 0; j < 8; ++j) {
        int c = k0 + j;
        float v = 0.f;
        if (c < AF) v = W[(size_t)c * 256 + col];
        else if (c >= 136 && c < 392) v = W[(size_t)(c - 3) * 256 + col];
        x[j] = v;
    }
    uint4 o;
    o.x = pack_bf2(x[0], x[1]); o.y = pack_bf2(x[2], x[3]);
    o.z = pack_bf2(x[4], x[5]); o.w = pack_bf2(x[6], x[7]);
    Wp[t] = o;
}

// ---------------------------------------------------------------------------
// K1 (MFMA, 64-row tile, 8 waves of 32x64 sub-tiles):
// inp = f_bonds(fp32)@W_i -> bf16. Per-wave resources identical to the
// proven 32-row body (acc[2][4], VGPR ~50-60) but half the barrier
// instances per row and 8 waves sharing Wp through L1.
// ---------------------------------------------------------------------------
__global__ __launch_bounds__(512, 4) void k_gemm_wi(const float* __restrict__ X,
                                                    const uint4* __restrict__ Wp,
                                                    u32* __restrict__ outb) {
    __shared__ char xs[64 * 512];  // stage 64*336=21504B; transpose 32768B
    const int blk = blockIdx.x;
    const int tid = threadIdx.x;
    const int lane = tid & 63, wid = tid >> 6;
    const int rlo = lane & 15, g = lane >> 4;
    const int wr = wid >> 2, wc = wid & 3;

    // stage: wave wid handles rows wid, wid+8, ... (8 rows)
    for (int r = wid; r < 64; r += 8) {
        const float* row = X + ((size_t)blk * 64 + r) * BF;
#pragma unroll
        for (int p = 0; p < 2; ++p) {
            int c = p * 128 + lane * 2;
            if (c < 160) {
                float v0 = (c < BF) ? row[c] : 0.f;
                float v1 = (c + 1 < BF) ? row[c + 1] : 0.f;
                *(u32*)(xs + r * 336 + c * 2) = pack_bf2(v0, v1);
            }
        }
    }
    __syncthreads();

    f32x4 acc[2][4] = {};
#pragma unroll
    for (int kb = 0; kb < 5; ++kb) {
        bf16x8 af[2], bfr[4];
#pragma unroll
        for (int rb = 0; rb < 2; ++rb) {
            int row = wr * 32 + rb * 16 + rlo;
            af[rb] = *(const bf16x8*)(xs + row * 336 + (kb * 4 + g) * 16);
        }
#pragma unroll
        for (int cb = 0; cb < 4; ++cb) {
            uint4 w = Wp[(size_t)(kb * 4 + g) * 256 + wc * 64 + cb * 16 + rlo];
            bfr[cb] = *(const bf16x8*)&w;
        }
#pragma unroll
        for (int rb = 0; rb < 2; ++rb)
#pragma unroll
            for (int cb = 0; cb < 4; ++cb)
                acc[rb][cb] = __builtin_amdgcn_mfma_f32_16x16x32_bf16(
                    af[rb], bfr[cb], acc[rb][cb], 0, 0, 0);
    }
    __syncthreads();  // stage dead; reuse for transpose
#pragma unroll
    for (int rb = 0; rb < 2; ++rb)
#pragma unroll
        for (int cb = 0; cb < 4; ++cb)
#pragma unroll
            for (int r = 0; r < 4; ++r)
                *(unsigned short*)(xs + tswz(wr * 32 + rb * 16 + g * 4 + r,
                                             wc * 64 + cb * 16 + rlo)) =
                    bf1(acc[rb][cb][r]);
    __syncthreads();
#pragma unroll
    for (int i = 0; i < 4; ++i) {
        int e = (i * 512 + tid) * 8;
        int row = e >> 8, col = e & 255;
        uint4 dv = *(const uint4*)(xs + tswz(row, col));
        *(uint4*)&outb[(((size_t)blk * 64 + row) * 256 + col) >> 1] = dv;
    }
}

// ---------------------------------------------------------------------------
// K2 (16B/lane): aggb[a,:] = sum_j msg(a2b[a][j])[:]
// ---------------------------------------------------------------------------
template <bool RELU_SRC>
__global__ __launch_bounds__(256) void k_agg(const u32* __restrict__ msgb,
                                             const int* __restrict__ a2b,
                                             u32* __restrict__ aggb) {
    const int tid = threadIdx.x;
    const int lane = tid & 63, wv = tid >> 6;
    const int half = lane >> 5, cl = lane & 31;
    const int a = blockIdx.x * 8 + wv * 2 + half;
    int bidx[MAXNB];
#pragma unroll
    for (int j = 0; j < MAXNB; ++j) bidx[j] = a2b[a * MAXNB + j];
    float s0 = 0.f, s1 = 0.f, s2 = 0.f, s3 = 0.f;
    float s4 = 0.f, s5 = 0.f, s6 = 0.f, s7 = 0.f;
#pragma unroll
    for (int j = 0; j < MAXNB; ++j) {
        uint4 mv = *(const uint4*)&msgb[(size_t)bidx[j] * 128 + cl * 4];
        float e0 = bf_lo(mv.x), e1 = bf_hi(mv.x), e2 = bf_lo(mv.y), e3 = bf_hi(mv.y);
        float e4 = bf_lo(mv.z), e5 = bf_hi(mv.z), e6 = bf_lo(mv.w), e7 = bf_hi(mv.w);
        if (RELU_SRC) {
            e0 = fmaxf(e0, 0.f); e1 = fmaxf(e1, 0.f);
            e2 = fmaxf(e2, 0.f); e3 = fmaxf(e3, 0.f);
            e4 = fmaxf(e4, 0.f); e5 = fmaxf(e5, 0.f);
            e6 = fmaxf(e6, 0.f); e7 = fmaxf(e7, 0.f);
        }
        s0 += e0; s1 += e1; s2 += e2; s3 += e3;
        s4 += e4; s5 += e5; s6 += e6; s7 += e7;
    }
    uint4 o;
    o.x = pack_bf2(s0, s1); o.y = pack_bf2(s2, s3);
    o.z = pack_bf2(s4, s5); o.w = pack_bf2(s6, s7);
    *(uint4*)&aggb[(size_t)a * 128 + cl * 4] = o;
}

// ---------------------------------------------------------------------------
// K3 (MFMA, 64-row tile, R12 structure + 16B/lane staging):
// msg_out = relu(inp + (agg[b2a] - msg(b2revb)) @ W_m)
// ---------------------------------------------------------------------------
template <bool RELU_SRC>
__global__ __launch_bounds__(256) void k_msg_update(
    const u32* __restrict__ inpb, const u32* __restrict__ aggb,
    const u32* __restrict__ msgb_in, const int* __restrict__ b2a,
    const int* __restrict__ b2revb, const uint4* __restrict__ Wp,
    u32* __restrict__ msgb_out) {
    __shared__ char xs[64 * 512];  // 32 KB bf16 [64][256]
    const int blk = blockIdx.x;
    const int tid = threadIdx.x;
    const int lane = tid & 63, wv = tid >> 6;
    const int rlo = lane & 15, g = lane >> 4;
    const int half = lane >> 5, cl = lane & 31;

    // preload this wave's 16 index pairs (rows wv+4i) into lanes 0..15
    int ia = 0, irv = 0;
    if (lane < 16) {
        int b = blk * 64 + wv + lane * 4;
        ia  = b2a[b];
        irv = b2revb[b];
    }
#pragma unroll
    for (int i = 0; i < 8; ++i) {
        const int aA  = __builtin_amdgcn_readlane(ia, i);
        const int aB  = __builtin_amdgcn_readlane(ia, i + 8);
        const int rvA = __builtin_amdgcn_readlane(irv, i);
        const int rvB = __builtin_amdgcn_readlane(irv, i + 8);
        const int a  = half ? aB : aA;
        const int rv = half ? rvB : rvA;
        const int r  = wv + (half ? (i + 8) : i) * 4;
        uint4 ga = *(const uint4*)&aggb[(size_t)a * 128 + cl * 4];
        uint4 gm = *(const uint4*)&msgb_in[(size_t)rv * 128 + cl * 4];
        float a0 = bf_lo(ga.x), a1 = bf_hi(ga.x), a2 = bf_lo(ga.y), a3 = bf_hi(ga.y);
        float a4 = bf_lo(ga.z), a5 = bf_hi(ga.z), a6 = bf_lo(ga.w), a7 = bf_hi(ga.w);
        float m0 = bf_lo(gm.x), m1 = bf_hi(gm.x), m2 = bf_lo(gm.y), m3 = bf_hi(gm.y);
        float m4 = bf_lo(gm.z), m5 = bf_hi(gm.z), m6 = bf_lo(gm.w), m7 = bf_hi(gm.w);
        if (RELU_SRC) {
            m0 = fmaxf(m0, 0.f); m1 = fmaxf(m1, 0.f);
            m2 = fmaxf(m2, 0.f); m3 = fmaxf(m3, 0.f);
            m4 = fmaxf(m4, 0.f); m5 = fmaxf(m5, 0.f);
            m6 = fmaxf(m6, 0.f); m7 = fmaxf(m7, 0.f);
        }
        uint4 pv;
        pv.x = pack_bf2(a0 - m0, a1 - m1);
        pv.y = pack_bf2(a2 - m2, a3 - m3);
        pv.z = pack_bf2(a4 - m4, a5 - m5);
        pv.w = pack_bf2(a6 - m6, a7 - m7);
        int schunk = cl ^ (r & 7);
        *(uint4*)(xs + r * 512 + (schunk << 4)) = pv;
    }
    __syncthreads();

    f32x4 acc[4][4] = {};
#pragma unroll
    for (int kb = 0; kb < 8; ++kb) {
        bf16x8 af[4], bfr[4];
#pragma unroll
        for (int rb = 0; rb < 4; ++rb) {
            int row = rb * 16 + rlo;
            int schunk = (kb * 4 + g) ^ (row & 7);
            af[rb] = *(const bf16x8*)(xs + row * 512 + (schunk << 4));
        }
#pragma unroll
        for (int cb = 0; cb < 4; ++cb) {
            uint4 w = Wp[(size_t)(kb * 4 + g) * 256 + wv * 64 + cb * 16 + rlo];
            bfr[cb] = *(const bf16x8*)&w;
        }
#pragma unroll
        for (int rb = 0; rb < 4; ++rb)
#pragma unroll
            for (int cb = 0; cb < 4; ++cb)
                acc[rb][cb] = __builtin_amdgcn_mfma_f32_16x16x32_bf16(
                    af[rb], bfr[cb], acc[rb][cb], 0, 0, 0);
    }
    __syncthreads();  // A-tile dead; reuse for transpose

#pragma unroll
    for (int rb = 0; rb < 4; ++rb)
#pragma unroll
        for (int cb = 0; cb < 4; ++cb)
#pragma unroll
            for (int r = 0; r < 4; ++r)
                ((unsigned short*)xs)[(rb * 16 + g * 4 + r) * 256 + wv * 64 + cb * 16 + rlo] =
                    bf1(acc[rb][cb][r]);
    __syncthreads();

#pragma unroll
    for (int i = 0; i < 8; ++i) {
        int e = (i * 256 + tid) * 8;
        int row = e >> 8, col = e & 255;
        uint4 dv = *(const uint4*)(xs + row * 512 + col * 2);
        size_t go = ((size_t)blk * 64 + row) * 256 + col;
        uint4 iv = *(const uint4*)&inpb[go >> 1];
        uint4 ov;
        ov.x = pack_bf2(fmaxf(bf_lo(dv.x) + bf_lo(iv.x), 0.f),
                        fmaxf(bf_hi(dv.x) + bf_hi(iv.x), 0.f));
        ov.y = pack_bf2(fmaxf(bf_lo(dv.y) + bf_lo(iv.y), 0.f),
                        fmaxf(bf_hi(dv.y) + bf_hi(iv.y), 0.f));
        ov.z = pack_bf2(fmaxf(bf_lo(dv.z) + bf_lo(iv.z), 0.f),
                        fmaxf(bf_hi(dv.z) + bf_hi(iv.z), 0.f));
        ov.w = pack_bf2(fmaxf(bf_lo(dv.w) + bf_lo(iv.w), 0.f),
                        fmaxf(bf_hi(dv.w) + bf_hi(iv.w), 0.f));
        *(uint4*)&msgb_out[go >> 1] = ov;
    }
}

// ---------------------------------------------------------------------------
// K4 (MFMA, 64-row tile, R8 body + a2b index-preload, fused agg):
// atom_h = relu([f_atoms | sum_j msg2(a2b)] @ W_a + b_a) -> bf16
// ---------------------------------------------------------------------------
__global__ __launch_bounds__(256) void k_atomh(
    const float* __restrict__ f_atoms, const u32* __restrict__ msgb,
    const int* __restrict__ a2b, const uint4* __restrict__ Wp,
    const float* __restrict__ ba, u32* __restrict__ athb) {
    __shared__ char xs[64 * 832];  // 53248B; transpose region (32768B) aliases
    const int blk = blockIdx.x;
    const int tid = threadIdx.x;
    const int lane = tid & 63, wv = tid >> 6;
    const int rlo = lane & 15, g = lane >> 4;

    // preload a2b for this wave's 16 rows (wv+4i): lane = i*8+j (j<6 valid)
    int idxA = 0, idxB = 0;
    {
        int i = lane >> 3, j = lane & 7;
        if (j < MAXNB) {
            idxA = a2b[(size_t)(blk * 64 + wv + i * 4) * MAXNB + j];
            idxB = a2b[(size_t)(blk * 64 + wv + (i + 8) * 4) * MAXNB + j];
        }
    }

#pragma unroll
    for (int i = 0; i < 16; ++i) {
        const int r = wv + i * 4;
        const int gr = blk * 64 + r;
        const float* fa = f_atoms + (size_t)gr * AF;
#pragma unroll
        for (int p = 0; p < 2; ++p) {
            int c = p * 128 + lane * 2;
            if (c < 136) {
                float v0 = (c < AF) ? fa[c] : 0.f;
                float v1 = (c + 1 < AF) ? fa[c + 1] : 0.f;
                *(u32*)(xs + r * 832 + c * 2) = pack_bf2(v0, v1);
            }
        }
        float s0 = 0.f, s1 = 0.f, s2 = 0.f, s3 = 0.f;
#pragma unroll
        for (int j = 0; j < MAXNB; ++j) {
            const int b = __builtin_amdgcn_readlane(i < 8 ? idxA : idxB,
                                                    ((i & 7) << 3) | j);
            uint2 mv = *(const uint2*)&msgb[(size_t)b * 128 + lane * 2];
            s0 += bf_lo(mv.x); s1 += bf_hi(mv.x);
            s2 += bf_lo(mv.y); s3 += bf_hi(mv.y);
        }
        uint2 o; o.x = pack_bf2(s0, s1); o.y = pack_bf2(s2, s3);
        *(uint2*)(xs + r * 832 + 272 + lane * 8) = o;
        if (lane < 6) {  // zero pad cols 392..415
            uint2 z = {0u, 0u};
            *(uint2*)(xs + r * 832 + 784 + lane * 8) = z;
        }
    }
    __syncthreads();

    f32x4 acc[4][4] = {};
#pragma unroll
    for (int kb = 0; kb < 13; ++kb) {
        bf16x8 af[4], bfr[4];
#pragma unroll
        for (int rb = 0; rb < 4; ++rb) {
            int row = rb * 16 + rlo;
            af[rb] = *(const bf16x8*)(xs + row * 832 + (kb * 4 + g) * 16);
        }
#pragma unroll
        for (int cb = 0; cb < 4; ++cb) {
            uint4 w = Wp[(size_t)(kb * 4 + g) * 256 + wv * 64 + cb * 16 + rlo];
            bfr[cb] = *(const bf16x8*)&w;
        }
#pragma unroll
        for (int rb = 0; rb < 4; ++rb)
#pragma unroll
            for (int cb = 0; cb < 4; ++cb)
                acc[rb][cb] = __builtin_amdgcn_mfma_f32_16x16x32_bf16(
                    af[rb], bfr[cb], acc[rb][cb], 0, 0, 0);
    }
    __syncthreads();
    float bcol[4];
#pragma unroll
    for (int cb = 0; cb < 4; ++cb) bcol[cb] = ba[wv * 64 + cb * 16 + rlo];
#pragma unroll
    for (int rb = 0; rb < 4; ++rb)
#pragma unroll
        for (int cb = 0; cb < 4; ++cb)
#pragma unroll
            for (int r = 0; r < 4; ++r)
                ((unsigned short*)xs)[(rb * 16 + g * 4 + r) * 256 + wv * 64 + cb * 16 + rlo] =
                    bf1(fmaxf(acc[rb][cb][r] + bcol[cb], 0.f));
    __syncthreads();
#pragma unroll
    for (int i = 0; i < 8; ++i) {
        int e = (i * 256 + tid) * 8;
        int row = e >> 8, col = e & 255;
        uint4 dv = *(const uint4*)(xs + row * 512 + col * 2);
        *(uint4*)&athb[(((size_t)blk * 64 + row) * 256 + col) >> 1] = dv;
    }
}

// ---------------------------------------------------------------------------
// K5 (16B/lane): per-molecule mean readout (atom_h bf16); sorted mol_index.
// ---------------------------------------------------------------------------
__global__ __launch_bounds__(256) void k_readout(const u32* __restrict__ athb,
                                                 const int* __restrict__ mol_index,
                                                 float* __restrict__ out) {
    __shared__ int s_lo, s_hi;
    __shared__ float red[8][256];
    const int m = blockIdx.x;
    const int tid = threadIdx.x;
    const int grp = tid >> 5, c4 = tid & 31;
    if (tid == 0) {
        int lo = 0, hi = NA;
        while (lo < hi) { int mid = (lo + hi) >> 1; if (mol_index[mid] < m) lo = mid + 1; else hi = mid; }
        s_lo = lo;
        int lo2 = lo, hi2 = NA;
        while (lo2 < hi2) { int mid = (lo2 + hi2) >> 1; if (mol_index[mid] < m + 1) lo2 = mid + 1; else hi2 = mid; }
        s_hi = lo2;
    }
    __syncthreads();
    const int lo = s_lo, hi = s_hi;
    float s[8] = {};
    for (int a = lo + grp; a < hi; a += 8) {
        uint4 v = *(const uint4*)&athb[(size_t)a * 128 + c4 * 4];
        s[0] += bf_lo(v.x); s[1] += bf_hi(v.x);
        s[2] += bf_lo(v.y); s[3] += bf_hi(v.y);
        s[4] += bf_lo(v.z); s[5] += bf_hi(v.z);
        s[6] += bf_lo(v.w); s[7] += bf_hi(v.w);
    }
#pragma unroll
    for (int k = 0; k < 8; ++k) red[grp][c4 * 8 + k] = s[k];
    __syncthreads();
#pragma unroll
    for (int st = 4; st >= 1; st >>= 1) {
        if (grp < st) {
#pragma unroll
            for (int k = 0; k < 8; ++k)
                red[grp][c4 * 8 + k] += red[grp + st][c4 * 8 + k];
        }
        __syncthreads();
    }
    if (tid < 32) {
        float inv = 1.0f / fmaxf((float)(hi - lo), 1.0f);
        float4 o0, o1;
        o0.x = red[0][c4 * 8 + 0] * inv; o0.y = red[0][c4 * 8 + 1] * inv;
        o0.z = red[0][c4 * 8 + 2] * inv; o0.w = red[0][c4 * 8 + 3] * inv;
        o1.x = red[0][c4 * 8 + 4] * inv; o1.y = red[0][c4 * 8 + 5] * inv;
        o1.z = red[0][c4 * 8 + 6] * inv; o1.w = red[0][c4 * 8 + 7] * inv;
        *(float4*)&out[(size_t)m * 256 + c4 * 8] = o0;
        *(float4*)&out[(size_t)m * 256 + c4 * 8 + 4] = o1;
    }
}

// ---------------------------------------------------------------------------
extern "C" void kernel_launch(void* const* d_in, const int* in_sizes, int n_in,
                              void* d_out, int out_size, void* d_ws, size_t ws_size,
                              hipStream_t stream) {
    const float* f_atoms = (const float*)d_in[0];
    const float* f_bonds = (const float*)d_in[1];
    const float* W_i     = (const float*)d_in[2];
    const float* W_m     = (const float*)d_in[3];
    const float* W_a     = (const float*)d_in[4];
    const float* b_a     = (const float*)d_in[5];
    const int* a2b       = (const int*)d_in[6];
    const int* b2a       = (const int*)d_in[7];
    const int* b2revb    = (const int*)d_in[8];
    const int* mol_index = (const int*)d_in[9];
    float* out = (float*)d_out;

    const size_t SZ_BH2 = (size_t)NB * H * 2;   // 128 MB bf16 message buf
    const size_t SZ_AG2 = (size_t)NA * H * 2;   // 32 MB bf16 agg
    const size_t SZ_WPM = 32 * 256 * 16;
    const size_t SZ_WPI = 20 * 256 * 16;
    const size_t SZ_WPA = 52 * 256 * 16;
    const size_t NEEDED = 3 * SZ_BH2 + SZ_AG2 + SZ_WPM + SZ_WPI + SZ_WPA;  // ~416 MB
    if (ws_size < NEEDED) return;  // diagnostic guard

    char* ws = (char*)d_ws;
    u32* inp    = (u32*)(ws);
    u32* msg1   = (u32*)(ws + SZ_BH2);
    u32* msg2   = (u32*)(ws + 2 * SZ_BH2);
    u32* aggb   = (u32*)(ws + 3 * SZ_BH2);
    uint4* WpM  = (uint4*)(ws + 3 * SZ_BH2 + SZ_AG2);
    uint4* WpI  = (uint4*)(ws + 3 * SZ_BH2 + SZ_AG2 + SZ_WPM);
    uint4* WpA  = (uint4*)(ws + 3 * SZ_BH2 + SZ_AG2 + SZ_WPM + SZ_WPI);
    u32* athb   = msg1;  // alias msg1 (dead by K4)

    // one-time weight packs
    k_pack_w<<<32, 256, 0, stream>>>(W_m, WpM, 256);
    k_pack_w<<<20, 256, 0, stream>>>(W_i, WpI, BF);
    k_pack_wa<<<52, 256, 0, stream>>>(W_a, WpA);

    // inp = f_bonds @ W_i (pre-activation, bf16); message0 = relu(inp) virtual
    k_gemm_wi<<<NB / 64, 512, 0, stream>>>(f_bonds, WpI, inp);

    // step 1
    k_agg<true><<<NA / 8, 256, 0, stream>>>(inp, a2b, aggb);
    k_msg_update<true><<<NB / 64, 256, 0, stream>>>(inp, aggb, inp, b2a, b2revb, WpM, msg1);

    // step 2
    k_agg<false><<<NA / 8, 256, 0, stream>>>(msg1, a2b, aggb);
    k_msg_update<false><<<NB / 64, 256, 0, stream>>>(inp, aggb, msg1, b2a, b2revb, WpM, msg2);

    // fused atom aggregation + W_a + relu
    k_atomh<<<NA / 64, 256, 0, stream>>>(f_atoms, msg2, a2b, WpA, b_a, athb);

    // per-molecule mean readout
    k_readout<<<NM, 256, 0, stream>>>((const u32*)athb, mol_index, out);
}

// Round 19
// 449.466 us; speedup vs baseline: 1.0268x; 1.0268x over previous
//
#include <hip/hip_runtime.h>
#include <cstdint>

#define NA 65536
#define NB 262144
#define MAXNB 6
#define H 256
#define BF 147
#define AF 133
#define NM 2048

typedef unsigned int u32;
typedef __attribute__((ext_vector_type(8))) short bf16x8;
typedef __attribute__((ext_vector_type(4))) float f32x4;

// bf16 helpers (manual, RNE)
__device__ __forceinline__ u32 pack_bf2(float a, float b) {
    u32 ua = __float_as_uint(a); ua = (ua + 0x7FFFu + ((ua >> 16) & 1u)) >> 16;
    u32 ub = __float_as_uint(b); ub = (ub + 0x7FFFu + ((ub >> 16) & 1u)) >> 16;
    return ua | (ub << 16);
}
__device__ __forceinline__ unsigned short bf1(float a) {
    u32 ua = __float_as_uint(a); return (unsigned short)((ua + 0x7FFFu + ((ua >> 16) & 1u)) >> 16);
}
__device__ __forceinline__ float bf_lo(u32 u) { return __uint_as_float(u << 16); }
__device__ __forceinline__ float bf_hi(u32 u) { return __uint_as_float(u & 0xFFFF0000u); }

// transpose-region swizzle (row stride 512B regions)
__device__ __forceinline__ int tswz(int row, int col) {
    int chunk = (col >> 3) ^ (((row >> 2) & 3) << 1);
    return row * 512 + (chunk << 4) + ((col & 7) << 1);
}

// ---------------------------------------------------------------------------
// K0: generic weight pack W[K][256] fp32 -> bf16 fragment layout (zero-pad K).
// ---------------------------------------------------------------------------
__global__ __launch_bounds__(256) void k_pack_w(const float* __restrict__ W,
                                                uint4* __restrict__ Wp, int K) {
    int t = blockIdx.x * 256 + threadIdx.x;
    int kbg = t >> 8, col = t & 255;
    int k0 = kbg * 8;
    float x[8];
#pragma unroll
    for (int j = 0; j < 8; ++j)
        x[j] = (k0 + j < K) ? W[(size_t)(k0 + j) * 256 + col] : 0.f;
    uint4 o;
    o.x = pack_bf2(x[0], x[1]); o.y = pack_bf2(x[2], x[3]);
    o.z = pack_bf2(x[4], x[5]); o.w = pack_bf2(x[6], x[7]);
    Wp[t] = o;
}

// ---------------------------------------------------------------------------
// K0c: W_a pack with 3-col shift (amsg block starts at padded col 136).
// ---------------------------------------------------------------------------
__global__ __launch_bounds__(256) void k_pack_wa(const float* __restrict__ W,
                                                 uint4* __restrict__ Wp) {
    int t = blockIdx.x * 256 + threadIdx.x;
    int kbg = t >> 8, col = t & 255;
    int k0 = kbg * 8;
    float x[8];
#pragma unroll
    for (int j = 0; j < 8; ++j) {
        int c = k0 + j;
        float v = 0.f;
        if (c < AF) v = W[(size_t)c * 256 + col];
        else if (c >= 136 && c < 392) v = W[(size_t)(c - 3) * 256 + col];
        x[j] = v;
    }
    uint4 o;
    o.x = pack_bf2(x[0], x[1]); o.y = pack_bf2(x[2], x[3]);
    o.z = pack_bf2(x[4], x[5]); o.w = pack_bf2(x[6], x[7]);
    Wp[t] = o;
}

// ---------------------------------------------------------------------------
// K1 (MFMA, 32-row tile, EXACT R9/R15 body — VGPR 32, occ 82%, 117us proven):
// inp = f_bonds(fp32)@W_i -> bf16. Occupancy beats ILP here (R16/R18 lesson).
// ---------------------------------------------------------------------------
__global__ __launch_bounds__(256, 8) void k_gemm_wi(const float* __restrict__ X,
                                                    const uint4* __restrict__ Wp,
                                                    u32* __restrict__ outb) {
    __shared__ char xs[32 * 512];  // stage 32*336=10752B; transpose 16384B
    const int blk = blockIdx.x;
    const int tid = threadIdx.x;
    const int lane = tid & 63, wv = tid >> 6;
    const int rlo = lane & 15, g = lane >> 4;

    for (int r = wv; r < 32; r += 4) {
        const float* row = X + ((size_t)blk * 32 + r) * BF;
#pragma unroll
        for (int p = 0; p < 2; ++p) {
            int c = p * 128 + lane * 2;
            if (c < 160) {
                float v0 = (c < BF) ? row[c] : 0.f;
                float v1 = (c + 1 < BF) ? row[c + 1] : 0.f;
                *(u32*)(xs + r * 336 + c * 2) = pack_bf2(v0, v1);
            }
        }
    }
    __syncthreads();

    f32x4 acc[2][4] = {};
#pragma unroll
    for (int kb = 0; kb < 5; ++kb) {
        bf16x8 af[2], bfr[4];
#pragma unroll
        for (int rb = 0; rb < 2; ++rb) {
            int row = rb * 16 + rlo;
            af[rb] = *(const bf16x8*)(xs + row * 336 + (kb * 4 + g) * 16);
        }
#pragma unroll
        for (int cb = 0; cb < 4; ++cb) {
            uint4 w = Wp[(size_t)(kb * 4 + g) * 256 + wv * 64 + cb * 16 + rlo];
            bfr[cb] = *(const bf16x8*)&w;
        }
#pragma unroll
        for (int rb = 0; rb < 2; ++rb)
#pragma unroll
            for (int cb = 0; cb < 4; ++cb)
                acc[rb][cb] = __builtin_amdgcn_mfma_f32_16x16x32_bf16(
                    af[rb], bfr[cb], acc[rb][cb], 0, 0, 0);
    }
    __syncthreads();  // stage dead; reuse for transpose
#pragma unroll
    for (int rb = 0; rb < 2; ++rb)
#pragma unroll
        for (int cb = 0; cb < 4; ++cb)
#pragma unroll
            for (int r = 0; r < 4; ++r)
                *(unsigned short*)(xs + tswz(rb * 16 + g * 4 + r, wv * 64 + cb * 16 + rlo)) =
                    bf1(acc[rb][cb][r]);
    __syncthreads();
#pragma unroll
    for (int i = 0; i < 4; ++i) {
        int e = (i * 256 + tid) * 8;
        int row = e >> 8, col = e & 255;
        uint4 dv = *(const uint4*)(xs + tswz(row, col));
        *(uint4*)&outb[(((size_t)blk * 32 + row) * 256 + col) >> 1] = dv;
    }
}

// ---------------------------------------------------------------------------
// K2 (16B/lane): aggb[a,:] = sum_j msg(a2b[a][j])[:]
// ---------------------------------------------------------------------------
template <bool RELU_SRC>
__global__ __launch_bounds__(256) void k_agg(const u32* __restrict__ msgb,
                                             const int* __restrict__ a2b,
                                             u32* __restrict__ aggb) {
    const int tid = threadIdx.x;
    const int lane = tid & 63, wv = tid >> 6;
    const int half = lane >> 5, cl = lane & 31;
    const int a = blockIdx.x * 8 + wv * 2 + half;
    int bidx[MAXNB];
#pragma unroll
    for (int j = 0; j < MAXNB; ++j) bidx[j] = a2b[a * MAXNB + j];
    float s0 = 0.f, s1 = 0.f, s2 = 0.f, s3 = 0.f;
    float s4 = 0.f, s5 = 0.f, s6 = 0.f, s7 = 0.f;
#pragma unroll
    for (int j = 0; j < MAXNB; ++j) {
        uint4 mv = *(const uint4*)&msgb[(size_t)bidx[j] * 128 + cl * 4];
        float e0 = bf_lo(mv.x), e1 = bf_hi(mv.x), e2 = bf_lo(mv.y), e3 = bf_hi(mv.y);
        float e4 = bf_lo(mv.z), e5 = bf_hi(mv.z), e6 = bf_lo(mv.w), e7 = bf_hi(mv.w);
        if (RELU_SRC) {
            e0 = fmaxf(e0, 0.f); e1 = fmaxf(e1, 0.f);
            e2 = fmaxf(e2, 0.f); e3 = fmaxf(e3, 0.f);
            e4 = fmaxf(e4, 0.f); e5 = fmaxf(e5, 0.f);
            e6 = fmaxf(e6, 0.f); e7 = fmaxf(e7, 0.f);
        }
        s0 += e0; s1 += e1; s2 += e2; s3 += e3;
        s4 += e4; s5 += e5; s6 += e6; s7 += e7;
    }
    uint4 o;
    o.x = pack_bf2(s0, s1); o.y = pack_bf2(s2, s3);
    o.z = pack_bf2(s4, s5); o.w = pack_bf2(s6, s7);
    *(uint4*)&aggb[(size_t)a * 128 + cl * 4] = o;
}

// ---------------------------------------------------------------------------
// K3 (MFMA, 64-row tile, R12 structure + 16B/lane staging):
// msg_out = relu(inp + (agg[b2a] - msg(b2revb)) @ W_m)
// ---------------------------------------------------------------------------
template <bool RELU_SRC>
__global__ __launch_bounds__(256) void k_msg_update(
    const u32* __restrict__ inpb, const u32* __restrict__ aggb,
    const u32* __restrict__ msgb_in, const int* __restrict__ b2a,
    const int* __restrict__ b2revb, const uint4* __restrict__ Wp,
    u32* __restrict__ msgb_out) {
    __shared__ char xs[64 * 512];  // 32 KB bf16 [64][256]
    const int blk = blockIdx.x;
    const int tid = threadIdx.x;
    const int lane = tid & 63, wv = tid >> 6;
    const int rlo = lane & 15, g = lane >> 4;
    const int half = lane >> 5, cl = lane & 31;

    // preload this wave's 16 index pairs (rows wv+4i) into lanes 0..15
    int ia = 0, irv = 0;
    if (lane < 16) {
        int b = blk * 64 + wv + lane * 4;
        ia  = b2a[b];
        irv = b2revb[b];
    }
#pragma unroll
    for (int i = 0; i < 8; ++i) {
        const int aA  = __builtin_amdgcn_readlane(ia, i);
        const int aB  = __builtin_amdgcn_readlane(ia, i + 8);
        const int rvA = __builtin_amdgcn_readlane(irv, i);
        const int rvB = __builtin_amdgcn_readlane(irv, i + 8);
        const int a  = half ? aB : aA;
        const int rv = half ? rvB : rvA;
        const int r  = wv + (half ? (i + 8) : i) * 4;
        uint4 ga = *(const uint4*)&aggb[(size_t)a * 128 + cl * 4];
        uint4 gm = *(const uint4*)&msgb_in[(size_t)rv * 128 + cl * 4];
        float a0 = bf_lo(ga.x), a1 = bf_hi(ga.x), a2 = bf_lo(ga.y), a3 = bf_hi(ga.y);
        float a4 = bf_lo(ga.z), a5 = bf_hi(ga.z), a6 = bf_lo(ga.w), a7 = bf_hi(ga.w);
        float m0 = bf_lo(gm.x), m1 = bf_hi(gm.x), m2 = bf_lo(gm.y), m3 = bf_hi(gm.y);
        float m4 = bf_lo(gm.z), m5 = bf_hi(gm.z), m6 = bf_lo(gm.w), m7 = bf_hi(gm.w);
        if (RELU_SRC) {
            m0 = fmaxf(m0, 0.f); m1 = fmaxf(m1, 0.f);
            m2 = fmaxf(m2, 0.f); m3 = fmaxf(m3, 0.f);
            m4 = fmaxf(m4, 0.f); m5 = fmaxf(m5, 0.f);
            m6 = fmaxf(m6, 0.f); m7 = fmaxf(m7, 0.f);
        }
        uint4 pv;
        pv.x = pack_bf2(a0 - m0, a1 - m1);
        pv.y = pack_bf2(a2 - m2, a3 - m3);
        pv.z = pack_bf2(a4 - m4, a5 - m5);
        pv.w = pack_bf2(a6 - m6, a7 - m7);
        int schunk = cl ^ (r & 7);
        *(uint4*)(xs + r * 512 + (schunk << 4)) = pv;
    }
    __syncthreads();

    f32x4 acc[4][4] = {};
#pragma unroll
    for (int kb = 0; kb < 8; ++kb) {
        bf16x8 af[4], bfr[4];
#pragma unroll
        for (int rb = 0; rb < 4; ++rb) {
            int row = rb * 16 + rlo;
            int schunk = (kb * 4 + g) ^ (row & 7);
            af[rb] = *(const bf16x8*)(xs + row * 512 + (schunk << 4));
        }
#pragma unroll
        for (int cb = 0; cb < 4; ++cb) {
            uint4 w = Wp[(size_t)(kb * 4 + g) * 256 + wv * 64 + cb * 16 + rlo];
            bfr[cb] = *(const bf16x8*)&w;
        }
#pragma unroll
        for (int rb = 0; rb < 4; ++rb)
#pragma unroll
            for (int cb = 0; cb < 4; ++cb)
                acc[rb][cb] = __builtin_amdgcn_mfma_f32_16x16x32_bf16(
                    af[rb], bfr[cb], acc[rb][cb], 0, 0, 0);
    }
    __syncthreads();  // A-tile dead; reuse for transpose

#pragma unroll
    for (int rb = 0; rb < 4; ++rb)
#pragma unroll
        for (int cb = 0; cb < 4; ++cb)
#pragma unroll
            for (int r = 0; r < 4; ++r)
                ((unsigned short*)xs)[(rb * 16 + g * 4 + r) * 256 + wv * 64 + cb * 16 + rlo] =
                    bf1(acc[rb][cb][r]);
    __syncthreads();

#pragma unroll
    for (int i = 0; i < 8; ++i) {
        int e = (i * 256 + tid) * 8;
        int row = e >> 8, col = e & 255;
        uint4 dv = *(const uint4*)(xs + row * 512 + col * 2);
        size_t go = ((size_t)blk * 64 + row) * 256 + col;
        uint4 iv = *(const uint4*)&inpb[go >> 1];
        uint4 ov;
        ov.x = pack_bf2(fmaxf(bf_lo(dv.x) + bf_lo(iv.x), 0.f),
                        fmaxf(bf_hi(dv.x) + bf_hi(iv.x), 0.f));
        ov.y = pack_bf2(fmaxf(bf_lo(dv.y) + bf_lo(iv.y), 0.f),
                        fmaxf(bf_hi(dv.y) + bf_hi(iv.y), 0.f));
        ov.z = pack_bf2(fmaxf(bf_lo(dv.z) + bf_lo(iv.z), 0.f),
                        fmaxf(bf_hi(dv.z) + bf_hi(iv.z), 0.f));
        ov.w = pack_bf2(fmaxf(bf_lo(dv.w) + bf_lo(iv.w), 0.f),
                        fmaxf(bf_hi(dv.w) + bf_hi(iv.w), 0.f));
        *(uint4*)&msgb_out[go >> 1] = ov;
    }
}

// ---------------------------------------------------------------------------
// K4 (MFMA, 64-row tile, fused agg with 16B/lane half-wave gathers):
// atom_h = relu([f_atoms | sum_j msg2(a2b)] @ W_a + b_a) -> bf16
// f_atoms staging unchanged; agg gathers now uint4 (lanes 0-31 row i,
// lanes 32-63 row i+8) — same j-order per element, bitwise-identical sums.
// ---------------------------------------------------------------------------
__global__ __launch_bounds__(256) void k_atomh(
    const float* __restrict__ f_atoms, const u32* __restrict__ msgb,
    const int* __restrict__ a2b, const uint4* __restrict__ Wp,
    const float* __restrict__ ba, u32* __restrict__ athb) {
    __shared__ char xs[64 * 832];  // 53248B; transpose region (32768B) aliases
    const int blk = blockIdx.x;
    const int tid = threadIdx.x;
    const int lane = tid & 63, wv = tid >> 6;
    const int rlo = lane & 15, g = lane >> 4;
    const int half = lane >> 5, cl = lane & 31;

    // preload a2b for this wave's 16 rows (wv+4i): lane = i*8+j (j<6 valid)
    int idxA = 0, idxB = 0;
    {
        int i = lane >> 3, j = lane & 7;
        if (j < MAXNB) {
            idxA = a2b[(size_t)(blk * 64 + wv + i * 4) * MAXNB + j];
            idxB = a2b[(size_t)(blk * 64 + wv + (i + 8) * 4) * MAXNB + j];
        }
    }

    // f_atoms staging + zero pad (full wave per row)
#pragma unroll
    for (int i = 0; i < 16; ++i) {
        const int r = wv + i * 4;
        const int gr = blk * 64 + r;
        const float* fa = f_atoms + (size_t)gr * AF;
#pragma unroll
        for (int p = 0; p < 2; ++p) {
            int c = p * 128 + lane * 2;
            if (c < 136) {
                float v0 = (c < AF) ? fa[c] : 0.f;
                float v1 = (c + 1 < AF) ? fa[c + 1] : 0.f;
                *(u32*)(xs + r * 832 + c * 2) = pack_bf2(v0, v1);
            }
        }
        if (lane < 6) {  // zero pad cols 392..415
            uint2 z = {0u, 0u};
            *(uint2*)(xs + r * 832 + 784 + lane * 8) = z;
        }
    }

    // fused agg: half-wave per row, uint4 gathers (rows wv+4i / wv+4(i+8))
#pragma unroll
    for (int i = 0; i < 8; ++i) {
        const int r = wv + (half ? (i + 8) : i) * 4;
        float s0 = 0.f, s1 = 0.f, s2 = 0.f, s3 = 0.f;
        float s4 = 0.f, s5 = 0.f, s6 = 0.f, s7 = 0.f;
#pragma unroll
        for (int j = 0; j < MAXNB; ++j) {
            const int bA = __builtin_amdgcn_readlane(idxA, (i << 3) | j);
            const int bB = __builtin_amdgcn_readlane(idxB, (i << 3) | j);
            const int b = half ? bB : bA;
            uint4 mv = *(const uint4*)&msgb[(size_t)b * 128 + cl * 4];
            s0 += bf_lo(mv.x); s1 += bf_hi(mv.x);
            s2 += bf_lo(mv.y); s3 += bf_hi(mv.y);
            s4 += bf_lo(mv.z); s5 += bf_hi(mv.z);
            s6 += bf_lo(mv.w); s7 += bf_hi(mv.w);
        }
        uint4 o;
        o.x = pack_bf2(s0, s1); o.y = pack_bf2(s2, s3);
        o.z = pack_bf2(s4, s5); o.w = pack_bf2(s6, s7);
        *(uint4*)(xs + r * 832 + 272 + cl * 16) = o;
    }
    __syncthreads();

    f32x4 acc[4][4] = {};
#pragma unroll
    for (int kb = 0; kb < 13; ++kb) {
        bf16x8 af[4], bfr[4];
#pragma unroll
        for (int rb = 0; rb < 4; ++rb) {
            int row = rb * 16 + rlo;
            af[rb] = *(const bf16x8*)(xs + row * 832 + (kb * 4 + g) * 16);
        }
#pragma unroll
        for (int cb = 0; cb < 4; ++cb) {
            uint4 w = Wp[(size_t)(kb * 4 + g) * 256 + wv * 64 + cb * 16 + rlo];
            bfr[cb] = *(const bf16x8*)&w;
        }
#pragma unroll
        for (int rb = 0; rb < 4; ++rb)
#pragma unroll
            for (int cb = 0; cb < 4; ++cb)
                acc[rb][cb] = __builtin_amdgcn_mfma_f32_16x16x32_bf16(
                    af[rb], bfr[cb], acc[rb][cb], 0, 0, 0);
    }
    __syncthreads();
    float bcol[4];
#pragma unroll
    for (int cb = 0; cb < 4; ++cb) bcol[cb] = ba[wv * 64 + cb * 16 + rlo];
#pragma unroll
    for (int rb = 0; rb < 4; ++rb)
#pragma unroll
        for (int cb = 0; cb < 4; ++cb)
#pragma unroll
            for (int r = 0; r < 4; ++r)
                ((unsigned short*)xs)[(rb * 16 + g * 4 + r) * 256 + wv * 64 + cb * 16 + rlo] =
                    bf1(fmaxf(acc[rb][cb][r] + bcol[cb], 0.f));
    __syncthreads();
#pragma unroll
    for (int i = 0; i < 8; ++i) {
        int e = (i * 256 + tid) * 8;
        int row = e >> 8, col = e & 255;
        uint4 dv = *(const uint4*)(xs + row * 512 + col * 2);
        *(uint4*)&athb[(((size_t)blk * 64 + row) * 256 + col) >> 1] = dv;
    }
}

// ---------------------------------------------------------------------------
// K5 (16B/lane): per-molecule mean readout (atom_h bf16); sorted mol_index.
// ---------------------------------------------------------------------------
__global__ __launch_bounds__(256) void k_readout(const u32* __restrict__ athb,
                                                 const int* __restrict__ mol_index,
                                                 float* __restrict__ out) {
    __shared__ int s_lo, s_hi;
    __shared__ float red[8][256];
    const int m = blockIdx.x;
    const int tid = threadIdx.x;
    const int grp = tid >> 5, c4 = tid & 31;
    if (tid == 0) {
        int lo = 0, hi = NA;
        while (lo < hi) { int mid = (lo + hi) >> 1; if (mol_index[mid] < m) lo = mid + 1; else hi = mid; }
        s_lo = lo;
        int lo2 = lo, hi2 = NA;
        while (lo2 < hi2) { int mid = (lo2 + hi2) >> 1; if (mol_index[mid] < m + 1) lo2 = mid + 1; else hi2 = mid; }
        s_hi = lo2;
    }
    __syncthreads();
    const int lo = s_lo, hi = s_hi;
    float s[8] = {};
    for (int a = lo + grp; a < hi; a += 8) {
        uint4 v = *(const uint4*)&athb[(size_t)a * 128 + c4 * 4];
        s[0] += bf_lo(v.x); s[1] += bf_hi(v.x);
        s[2] += bf_lo(v.y); s[3] += bf_hi(v.y);
        s[4] += bf_lo(v.z); s[5] += bf_hi(v.z);
        s[6] += bf_lo(v.w); s[7] += bf_hi(v.w);
    }
#pragma unroll
    for (int k = 0; k < 8; ++k) red[grp][c4 * 8 + k] = s[k];
    __syncthreads();
#pragma unroll
    for (int st = 4; st >= 1; st >>= 1) {
        if (grp < st) {
#pragma unroll
            for (int k = 0; k < 8; ++k)
                red[grp][c4 * 8 + k] += red[grp + st][c4 * 8 + k];
        }
        __syncthreads();
    }
    if (tid < 32) {
        float inv = 1.0f / fmaxf((float)(hi - lo), 1.0f);
        float4 o0, o1;
        o0.x = red[0][c4 * 8 + 0] * inv; o0.y = red[0][c4 * 8 + 1] * inv;
        o0.z = red[0][c4 * 8 + 2] * inv; o0.w = red[0][c4 * 8 + 3] * inv;
        o1.x = red[0][c4 * 8 + 4] * inv; o1.y = red[0][c4 * 8 + 5] * inv;
        o1.z = red[0][c4 * 8 + 6] * inv; o1.w = red[0][c4 * 8 + 7] * inv;
        *(float4*)&out[(size_t)m * 256 + c4 * 8] = o0;
        *(float4*)&out[(size_t)m * 256 + c4 * 8 + 4] = o1;
    }
}

// ---------------------------------------------------------------------------
extern "C" void kernel_launch(void* const* d_in, const int* in_sizes, int n_in,
                              void* d_out, int out_size, void* d_ws, size_t ws_size,
                              hipStream_t stream) {
    const float* f_atoms = (const float*)d_in[0];
    const float* f_bonds = (const float*)d_in[1];
    const float* W_i     = (const float*)d_in[2];
    const float* W_m     = (const float*)d_in[3];
    const float* W_a     = (const float*)d_in[4];
    const float* b_a     = (const float*)d_in[5];
    const int* a2b       = (const int*)d_in[6];
    const int* b2a       = (const int*)d_in[7];
    const int* b2revb    = (const int*)d_in[8];
    const int* mol_index = (const int*)d_in[9];
    float* out = (float*)d_out;

    const size_t SZ_BH2 = (size_t)NB * H * 2;   // 128 MB bf16 message buf
    const size_t SZ_AG2 = (size_t)NA * H * 2;   // 32 MB bf16 agg
    const size_t SZ_WPM = 32 * 256 * 16;
    const size_t SZ_WPI = 20 * 256 * 16;
    const size_t SZ_WPA = 52 * 256 * 16;
    const size_t NEEDED = 3 * SZ_BH2 + SZ_AG2 + SZ_WPM + SZ_WPI + SZ_WPA;  // ~416 MB
    if (ws_size < NEEDED) return;  // diagnostic guard

    char* ws = (char*)d_ws;
    u32* inp    = (u32*)(ws);
    u32* msg1   = (u32*)(ws + SZ_BH2);
    u32* msg2   = (u32*)(ws + 2 * SZ_BH2);
    u32* aggb   = (u32*)(ws + 3 * SZ_BH2);
    uint4* WpM  = (uint4*)(ws + 3 * SZ_BH2 + SZ_AG2);
    uint4* WpI  = (uint4*)(ws + 3 * SZ_BH2 + SZ_AG2 + SZ_WPM);
    uint4* WpA  = (uint4*)(ws + 3 * SZ_BH2 + SZ_AG2 + SZ_WPM + SZ_WPI);
    u32* athb   = msg1;  // alias msg1 (dead by K4)

    // one-time weight packs
    k_pack_w<<<32, 256, 0, stream>>>(W_m, WpM, 256);
    k_pack_w<<<20, 256, 0, stream>>>(W_i, WpI, BF);
    k_pack_wa<<<52, 256, 0, stream>>>(W_a, WpA);

    // inp = f_bonds @ W_i (pre-activation, bf16); message0 = relu(inp) virtual
    k_gemm_wi<<<NB / 32, 256, 0, stream>>>(f_bonds, WpI, inp);

    // step 1
    k_agg<true><<<NA / 8, 256, 0, stream>>>(inp, a2b, aggb);
    k_msg_update<true><<<NB / 64, 256, 0, stream>>>(inp, aggb, inp, b2a, b2revb, WpM, msg1);

    // step 2
    k_agg<false><<<NA / 8, 256, 0, stream>>>(msg1, a2b, aggb);
    k_msg_update<false><<<NB / 64, 256, 0, stream>>>(inp, aggb, msg1, b2a, b2revb, WpM, msg2);

    // fused atom aggregation + W_a + relu
    k_atomh<<<NA / 64, 256, 0, stream>>>(f_atoms, msg2, a2b, WpA, b_a, athb);

    // per-molecule mean readout
    k_readout<<<NM, 256, 0, stream>>>((const u32*)athb, mol_index, out);
}

// Round 20
// 448.121 us; speedup vs baseline: 1.0299x; 1.0030x over previous
//
#include <hip/hip_runtime.h>
#include <cstdint>

#define NA 65536
#define NB 262144
#define MAXNB 6
#define H 256
#define BF 147
#define AF 133
#define NM 2048

typedef unsigned int u32;
typedef __attribute__((ext_vector_type(8))) short bf16x8;
typedef __attribute__((ext_vector_type(4))) float f32x4;

// bf16 helpers (manual, RNE)
__device__ __forceinline__ u32 pack_bf2(float a, float b) {
    u32 ua = __float_as_uint(a); ua = (ua + 0x7FFFu + ((ua >> 16) & 1u)) >> 16;
    u32 ub = __float_as_uint(b); ub = (ub + 0x7FFFu + ((ub >> 16) & 1u)) >> 16;
    return ua | (ub << 16);
}
__device__ __forceinline__ unsigned short bf1(float a) {
    u32 ua = __float_as_uint(a); return (unsigned short)((ua + 0x7FFFu + ((ua >> 16) & 1u)) >> 16);
}
__device__ __forceinline__ float bf_lo(u32 u) { return __uint_as_float(u << 16); }
__device__ __forceinline__ float bf_hi(u32 u) { return __uint_as_float(u & 0xFFFF0000u); }

// transpose-region swizzle (row stride 512B regions)
__device__ __forceinline__ int tswz(int row, int col) {
    int chunk = (col >> 3) ^ (((row >> 2) & 3) << 1);
    return row * 512 + (chunk << 4) + ((col & 7) << 1);
}

// ---------------------------------------------------------------------------
// K0: generic weight pack W[K][256] fp32 -> bf16 fragment layout (zero-pad K).
// ---------------------------------------------------------------------------
__global__ __launch_bounds__(256) void k_pack_w(const float* __restrict__ W,
                                                uint4* __restrict__ Wp, int K) {
    int t = blockIdx.x * 256 + threadIdx.x;
    int kbg = t >> 8, col = t & 255;
    int k0 = kbg * 8;
    float x[8];
#pragma unroll
    for (int j = 0; j < 8; ++j)
        x[j] = (k0 + j < K) ? W[(size_t)(k0 + j) * 256 + col] : 0.f;
    uint4 o;
    o.x = pack_bf2(x[0], x[1]); o.y = pack_bf2(x[2], x[3]);
    o.z = pack_bf2(x[4], x[5]); o.w = pack_bf2(x[6], x[7]);
    Wp[t] = o;
}

// ---------------------------------------------------------------------------
// K0c: W_a pack with 3-col shift (amsg block starts at padded col 136).
// ---------------------------------------------------------------------------
__global__ __launch_bounds__(256) void k_pack_wa(const float* __restrict__ W,
                                                 uint4* __restrict__ Wp) {
    int t = blockIdx.x * 256 + threadIdx.x;
    int kbg = t >> 8, col = t & 255;
    int k0 = kbg * 8;
    float x[8];
#pragma unroll
    for (int j = 0; j < 8; ++j) {
        int c = k0 + j;
        float v = 0.f;
        if (c < AF) v = W[(size_t)c * 256 + col];
        else if (c >= 136 && c < 392) v = W[(size_t)(c - 3) * 256 + col];
        x[j] = v;
    }
    uint4 o;
    o.x = pack_bf2(x[0], x[1]); o.y = pack_bf2(x[2], x[3]);
    o.z = pack_bf2(x[4], x[5]); o.w = pack_bf2(x[6], x[7]);
    Wp[t] = o;
}

// ---------------------------------------------------------------------------
// K1 (MFMA, 32-row tile, R9 body + exact-slot staging):
// inp = f_bonds(fp32)@W_i -> bf16. Staging: 2560 float2 slots (32 rows x 80),
// 10 per thread, zero dead lanes (old scheme idled 48/64 lanes on pass 2).
// ---------------------------------------------------------------------------
__global__ __launch_bounds__(256, 8) void k_gemm_wi(const float* __restrict__ X,
                                                    const uint4* __restrict__ Wp,
                                                    u32* __restrict__ outb) {
    __shared__ char xs[32 * 512];  // stage 32*336=10752B; transpose 16384B
    const int blk = blockIdx.x;
    const int tid = threadIdx.x;
    const int lane = tid & 63, wv = tid >> 6;
    const int rlo = lane & 15, g = lane >> 4;

    // exact staging: slot s in [0,2560): row = s/80, c2 = s%80 (cols 2*c2, 2*c2+1)
#pragma unroll
    for (int k = 0; k < 10; ++k) {
        int s = tid + k * 256;
        int r = s / 80, c2 = s - r * 80;
        int c = c2 * 2;
        const float* row = X + ((size_t)blk * 32 + r) * BF;
        float v0 = (c < BF) ? row[c] : 0.f;
        float v1 = (c + 1 < BF) ? row[c + 1] : 0.f;
        *(u32*)(xs + r * 336 + c * 2) = pack_bf2(v0, v1);
    }
    __syncthreads();

    f32x4 acc[2][4] = {};
#pragma unroll
    for (int kb = 0; kb < 5; ++kb) {
        bf16x8 af[2], bfr[4];
#pragma unroll
        for (int rb = 0; rb < 2; ++rb) {
            int row = rb * 16 + rlo;
            af[rb] = *(const bf16x8*)(xs + row * 336 + (kb * 4 + g) * 16);
        }
#pragma unroll
        for (int cb = 0; cb < 4; ++cb) {
            uint4 w = Wp[(size_t)(kb * 4 + g) * 256 + wv * 64 + cb * 16 + rlo];
            bfr[cb] = *(const bf16x8*)&w;
        }
#pragma unroll
        for (int rb = 0; rb < 2; ++rb)
#pragma unroll
            for (int cb = 0; cb < 4; ++cb)
                acc[rb][cb] = __builtin_amdgcn_mfma_f32_16x16x32_bf16(
                    af[rb], bfr[cb], acc[rb][cb], 0, 0, 0);
    }
    __syncthreads();  // stage dead; reuse for transpose
#pragma unroll
    for (int rb = 0; rb < 2; ++rb)
#pragma unroll
        for (int cb = 0; cb < 4; ++cb)
#pragma unroll
            for (int r = 0; r < 4; ++r)
                *(unsigned short*)(xs + tswz(rb * 16 + g * 4 + r, wv * 64 + cb * 16 + rlo)) =
                    bf1(acc[rb][cb][r]);
    __syncthreads();
#pragma unroll
    for (int i = 0; i < 4; ++i) {
        int e = (i * 256 + tid) * 8;
        int row = e >> 8, col = e & 255;
        uint4 dv = *(const uint4*)(xs + tswz(row, col));
        *(uint4*)&outb[(((size_t)blk * 32 + row) * 256 + col) >> 1] = dv;
    }
}

// ---------------------------------------------------------------------------
// K2 (16B/lane): aggb[a,:] = sum_j msg(a2b[a][j])[:]
// ---------------------------------------------------------------------------
template <bool RELU_SRC>
__global__ __launch_bounds__(256) void k_agg(const u32* __restrict__ msgb,
                                             const int* __restrict__ a2b,
                                             u32* __restrict__ aggb) {
    const int tid = threadIdx.x;
    const int lane = tid & 63, wv = tid >> 6;
    const int half = lane >> 5, cl = lane & 31;
    const int a = blockIdx.x * 8 + wv * 2 + half;
    int bidx[MAXNB];
#pragma unroll
    for (int j = 0; j < MAXNB; ++j) bidx[j] = a2b[a * MAXNB + j];
    float s0 = 0.f, s1 = 0.f, s2 = 0.f, s3 = 0.f;
    float s4 = 0.f, s5 = 0.f, s6 = 0.f, s7 = 0.f;
#pragma unroll
    for (int j = 0; j < MAXNB; ++j) {
        uint4 mv = *(const uint4*)&msgb[(size_t)bidx[j] * 128 + cl * 4];
        float e0 = bf_lo(mv.x), e1 = bf_hi(mv.x), e2 = bf_lo(mv.y), e3 = bf_hi(mv.y);
        float e4 = bf_lo(mv.z), e5 = bf_hi(mv.z), e6 = bf_lo(mv.w), e7 = bf_hi(mv.w);
        if (RELU_SRC) {
            e0 = fmaxf(e0, 0.f); e1 = fmaxf(e1, 0.f);
            e2 = fmaxf(e2, 0.f); e3 = fmaxf(e3, 0.f);
            e4 = fmaxf(e4, 0.f); e5 = fmaxf(e5, 0.f);
            e6 = fmaxf(e6, 0.f); e7 = fmaxf(e7, 0.f);
        }
        s0 += e0; s1 += e1; s2 += e2; s3 += e3;
        s4 += e4; s5 += e5; s6 += e6; s7 += e7;
    }
    uint4 o;
    o.x = pack_bf2(s0, s1); o.y = pack_bf2(s2, s3);
    o.z = pack_bf2(s4, s5); o.w = pack_bf2(s6, s7);
    *(uint4*)&aggb[(size_t)a * 128 + cl * 4] = o;
}

// ---------------------------------------------------------------------------
// K3 (MFMA, 64-row tile, R12 structure + 16B/lane staging):
// msg_out = relu(inp + (agg[b2a] - msg(b2revb)) @ W_m)
// ---------------------------------------------------------------------------
template <bool RELU_SRC>
__global__ __launch_bounds__(256) void k_msg_update(
    const u32* __restrict__ inpb, const u32* __restrict__ aggb,
    const u32* __restrict__ msgb_in, const int* __restrict__ b2a,
    const int* __restrict__ b2revb, const uint4* __restrict__ Wp,
    u32* __restrict__ msgb_out) {
    __shared__ char xs[64 * 512];  // 32 KB bf16 [64][256]
    const int blk = blockIdx.x;
    const int tid = threadIdx.x;
    const int lane = tid & 63, wv = tid >> 6;
    const int rlo = lane & 15, g = lane >> 4;
    const int half = lane >> 5, cl = lane & 31;

    // preload this wave's 16 index pairs (rows wv+4i) into lanes 0..15
    int ia = 0, irv = 0;
    if (lane < 16) {
        int b = blk * 64 + wv + lane * 4;
        ia  = b2a[b];
        irv = b2revb[b];
    }
#pragma unroll
    for (int i = 0; i < 8; ++i) {
        const int aA  = __builtin_amdgcn_readlane(ia, i);
        const int aB  = __builtin_amdgcn_readlane(ia, i + 8);
        const int rvA = __builtin_amdgcn_readlane(irv, i);
        const int rvB = __builtin_amdgcn_readlane(irv, i + 8);
        const int a  = half ? aB : aA;
        const int rv = half ? rvB : rvA;
        const int r  = wv + (half ? (i + 8) : i) * 4;
        uint4 ga = *(const uint4*)&aggb[(size_t)a * 128 + cl * 4];
        uint4 gm = *(const uint4*)&msgb_in[(size_t)rv * 128 + cl * 4];
        float a0 = bf_lo(ga.x), a1 = bf_hi(ga.x), a2 = bf_lo(ga.y), a3 = bf_hi(ga.y);
        float a4 = bf_lo(ga.z), a5 = bf_hi(ga.z), a6 = bf_lo(ga.w), a7 = bf_hi(ga.w);
        float m0 = bf_lo(gm.x), m1 = bf_hi(gm.x), m2 = bf_lo(gm.y), m3 = bf_hi(gm.y);
        float m4 = bf_lo(gm.z), m5 = bf_hi(gm.z), m6 = bf_lo(gm.w), m7 = bf_hi(gm.w);
        if (RELU_SRC) {
            m0 = fmaxf(m0, 0.f); m1 = fmaxf(m1, 0.f);
            m2 = fmaxf(m2, 0.f); m3 = fmaxf(m3, 0.f);
            m4 = fmaxf(m4, 0.f); m5 = fmaxf(m5, 0.f);
            m6 = fmaxf(m6, 0.f); m7 = fmaxf(m7, 0.f);
        }
        uint4 pv;
        pv.x = pack_bf2(a0 - m0, a1 - m1);
        pv.y = pack_bf2(a2 - m2, a3 - m3);
        pv.z = pack_bf2(a4 - m4, a5 - m5);
        pv.w = pack_bf2(a6 - m6, a7 - m7);
        int schunk = cl ^ (r & 7);
        *(uint4*)(xs + r * 512 + (schunk << 4)) = pv;
    }
    __syncthreads();

    f32x4 acc[4][4] = {};
#pragma unroll
    for (int kb = 0; kb < 8; ++kb) {
        bf16x8 af[4], bfr[4];
#pragma unroll
        for (int rb = 0; rb < 4; ++rb) {
            int row = rb * 16 + rlo;
            int schunk = (kb * 4 + g) ^ (row & 7);
            af[rb] = *(const bf16x8*)(xs + row * 512 + (schunk << 4));
        }
#pragma unroll
        for (int cb = 0; cb < 4; ++cb) {
            uint4 w = Wp[(size_t)(kb * 4 + g) * 256 + wv * 64 + cb * 16 + rlo];
            bfr[cb] = *(const bf16x8*)&w;
        }
#pragma unroll
        for (int rb = 0; rb < 4; ++rb)
#pragma unroll
            for (int cb = 0; cb < 4; ++cb)
                acc[rb][cb] = __builtin_amdgcn_mfma_f32_16x16x32_bf16(
                    af[rb], bfr[cb], acc[rb][cb], 0, 0, 0);
    }
    __syncthreads();  // A-tile dead; reuse for transpose

#pragma unroll
    for (int rb = 0; rb < 4; ++rb)
#pragma unroll
        for (int cb = 0; cb < 4; ++cb)
#pragma unroll
            for (int r = 0; r < 4; ++r)
                ((unsigned short*)xs)[(rb * 16 + g * 4 + r) * 256 + wv * 64 + cb * 16 + rlo] =
                    bf1(acc[rb][cb][r]);
    __syncthreads();

#pragma unroll
    for (int i = 0; i < 8; ++i) {
        int e = (i * 256 + tid) * 8;
        int row = e >> 8, col = e & 255;
        uint4 dv = *(const uint4*)(xs + row * 512 + col * 2);
        size_t go = ((size_t)blk * 64 + row) * 256 + col;
        uint4 iv = *(const uint4*)&inpb[go >> 1];
        uint4 ov;
        ov.x = pack_bf2(fmaxf(bf_lo(dv.x) + bf_lo(iv.x), 0.f),
                        fmaxf(bf_hi(dv.x) + bf_hi(iv.x), 0.f));
        ov.y = pack_bf2(fmaxf(bf_lo(dv.y) + bf_lo(iv.y), 0.f),
                        fmaxf(bf_hi(dv.y) + bf_hi(iv.y), 0.f));
        ov.z = pack_bf2(fmaxf(bf_lo(dv.z) + bf_lo(iv.z), 0.f),
                        fmaxf(bf_hi(dv.z) + bf_hi(iv.z), 0.f));
        ov.w = pack_bf2(fmaxf(bf_lo(dv.w) + bf_lo(iv.w), 0.f),
                        fmaxf(bf_hi(dv.w) + bf_hi(iv.w), 0.f));
        *(uint4*)&msgb_out[go >> 1] = ov;
    }
}

// ---------------------------------------------------------------------------
// K4 (MFMA, 64-row tile, fused agg with 16B/lane half-wave gathers):
// atom_h = relu([f_atoms | sum_j msg2(a2b)] @ W_a + b_a) -> bf16
// ---------------------------------------------------------------------------
__global__ __launch_bounds__(256) void k_atomh(
    const float* __restrict__ f_atoms, const u32* __restrict__ msgb,
    const int* __restrict__ a2b, const uint4* __restrict__ Wp,
    const float* __restrict__ ba, u32* __restrict__ athb) {
    __shared__ char xs[64 * 832];  // 53248B; transpose region (32768B) aliases
    const int blk = blockIdx.x;
    const int tid = threadIdx.x;
    const int lane = tid & 63, wv = tid >> 6;
    const int rlo = lane & 15, g = lane >> 4;
    const int half = lane >> 5, cl = lane & 31;

    // preload a2b for this wave's 16 rows (wv+4i): lane = i*8+j (j<6 valid)
    int idxA = 0, idxB = 0;
    {
        int i = lane >> 3, j = lane & 7;
        if (j < MAXNB) {
            idxA = a2b[(size_t)(blk * 64 + wv + i * 4) * MAXNB + j];
            idxB = a2b[(size_t)(blk * 64 + wv + (i + 8) * 4) * MAXNB + j];
        }
    }

    // f_atoms staging + zero pad (full wave per row)
#pragma unroll
    for (int i = 0; i < 16; ++i) {
        const int r = wv + i * 4;
        const int gr = blk * 64 + r;
        const float* fa = f_atoms + (size_t)gr * AF;
#pragma unroll
        for (int p = 0; p < 2; ++p) {
            int c = p * 128 + lane * 2;
            if (c < 136) {
                float v0 = (c < AF) ? fa[c] : 0.f;
                float v1 = (c + 1 < AF) ? fa[c + 1] : 0.f;
                *(u32*)(xs + r * 832 + c * 2) = pack_bf2(v0, v1);
            }
        }
        if (lane < 6) {  // zero pad cols 392..415
            uint2 z = {0u, 0u};
            *(uint2*)(xs + r * 832 + 784 + lane * 8) = z;
        }
    }

    // fused agg: half-wave per row, uint4 gathers (rows wv+4i / wv+4(i+8))
#pragma unroll
    for (int i = 0; i < 8; ++i) {
        const int r = wv + (half ? (i + 8) : i) * 4;
        float s0 = 0.f, s1 = 0.f, s2 = 0.f, s3 = 0.f;
        float s4 = 0.f, s5 = 0.f, s6 = 0.f, s7 = 0.f;
#pragma unroll
        for (int j = 0; j < MAXNB; ++j) {
            const int bA = __builtin_amdgcn_readlane(idxA, (i << 3) | j);
            const int bB = __builtin_amdgcn_readlane(idxB, (i << 3) | j);
            const int b = half ? bB : bA;
            uint4 mv = *(const uint4*)&msgb[(size_t)b * 128 + cl * 4];
            s0 += bf_lo(mv.x); s1 += bf_hi(mv.x);
            s2 += bf_lo(mv.y); s3 += bf_hi(mv.y);
            s4 += bf_lo(mv.z); s5 += bf_hi(mv.z);
            s6 += bf_lo(mv.w); s7 += bf_hi(mv.w);
        }
        uint4 o;
        o.x = pack_bf2(s0, s1); o.y = pack_bf2(s2, s3);
        o.z = pack_bf2(s4, s5); o.w = pack_bf2(s6, s7);
        *(uint4*)(xs + r * 832 + 272 + cl * 16) = o;
    }
    __syncthreads();

    f32x4 acc[4][4] = {};
#pragma unroll
    for (int kb = 0; kb < 13; ++kb) {
        bf16x8 af[4], bfr[4];
#pragma unroll
        for (int rb = 0; rb < 4; ++rb) {
            int row = rb * 16 + rlo;
            af[rb] = *(const bf16x8*)(xs + row * 832 + (kb * 4 + g) * 16);
        }
#pragma unroll
        for (int cb = 0; cb < 4; ++cb) {
            uint4 w = Wp[(size_t)(kb * 4 + g) * 256 + wv * 64 + cb * 16 + rlo];
            bfr[cb] = *(const bf16x8*)&w;
        }
#pragma unroll
        for (int rb = 0; rb < 4; ++rb)
#pragma unroll
            for (int cb = 0; cb < 4; ++cb)
                acc[rb][cb] = __builtin_amdgcn_mfma_f32_16x16x32_bf16(
                    af[rb], bfr[cb], acc[rb][cb], 0, 0, 0);
    }
    __syncthreads();
    float bcol[4];
#pragma unroll
    for (int cb = 0; cb < 4; ++cb) bcol[cb] = ba[wv * 64 + cb * 16 + rlo];
#pragma unroll
    for (int rb = 0; rb < 4; ++rb)
#pragma unroll
        for (int cb = 0; cb < 4; ++cb)
#pragma unroll
            for (int r = 0; r < 4; ++r)
                ((unsigned short*)xs)[(rb * 16 + g * 4 + r) * 256 + wv * 64 + cb * 16 + rlo] =
                    bf1(fmaxf(acc[rb][cb][r] + bcol[cb], 0.f));
    __syncthreads();
#pragma unroll
    for (int i = 0; i < 8; ++i) {
        int e = (i * 256 + tid) * 8;
        int row = e >> 8, col = e & 255;
        uint4 dv = *(const uint4*)(xs + row * 512 + col * 2);
        *(uint4*)&athb[(((size_t)blk * 64 + row) * 256 + col) >> 1] = dv;
    }
}

// ---------------------------------------------------------------------------
// K5 (16B/lane): per-molecule mean readout (atom_h bf16); sorted mol_index.
// ---------------------------------------------------------------------------
__global__ __launch_bounds__(256) void k_readout(const u32* __restrict__ athb,
                                                 const int* __restrict__ mol_index,
                                                 float* __restrict__ out) {
    __shared__ int s_lo, s_hi;
    __shared__ float red[8][256];
    const int m = blockIdx.x;
    const int tid = threadIdx.x;
    const int grp = tid >> 5, c4 = tid & 31;
    if (tid == 0) {
        int lo = 0, hi = NA;
        while (lo < hi) { int mid = (lo + hi) >> 1; if (mol_index[mid] < m) lo = mid + 1; else hi = mid; }
        s_lo = lo;
        int lo2 = lo, hi2 = NA;
        while (lo2 < hi2) { int mid = (lo2 + hi2) >> 1; if (mol_index[mid] < m + 1) lo2 = mid + 1; else hi2 = mid; }
        s_hi = lo2;
    }
    __syncthreads();
    const int lo = s_lo, hi = s_hi;
    float s[8] = {};
    for (int a = lo + grp; a < hi; a += 8) {
        uint4 v = *(const uint4*)&athb[(size_t)a * 128 + c4 * 4];
        s[0] += bf_lo(v.x); s[1] += bf_hi(v.x);
        s[2] += bf_lo(v.y); s[3] += bf_hi(v.y);
        s[4] += bf_lo(v.z); s[5] += bf_hi(v.z);
        s[6] += bf_lo(v.w); s[7] += bf_hi(v.w);
    }
#pragma unroll
    for (int k = 0; k < 8; ++k) red[grp][c4 * 8 + k] = s[k];
    __syncthreads();
#pragma unroll
    for (int st = 4; st >= 1; st >>= 1) {
        if (grp < st) {
#pragma unroll
            for (int k = 0; k < 8; ++k)
                red[grp][c4 * 8 + k] += red[grp + st][c4 * 8 + k];
        }
        __syncthreads();
    }
    if (tid < 32) {
        float inv = 1.0f / fmaxf((float)(hi - lo), 1.0f);
        float4 o0, o1;
        o0.x = red[0][c4 * 8 + 0] * inv; o0.y = red[0][c4 * 8 + 1] * inv;
        o0.z = red[0][c4 * 8 + 2] * inv; o0.w = red[0][c4 * 8 + 3] * inv;
        o1.x = red[0][c4 * 8 + 4] * inv; o1.y = red[0][c4 * 8 + 5] * inv;
        o1.z = red[0][c4 * 8 + 6] * inv; o1.w = red[0][c4 * 8 + 7] * inv;
        *(float4*)&out[(size_t)m * 256 + c4 * 8] = o0;
        *(float4*)&out[(size_t)m * 256 + c4 * 8 + 4] = o1;
    }
}

// ---------------------------------------------------------------------------
extern "C" void kernel_launch(void* const* d_in, const int* in_sizes, int n_in,
                              void* d_out, int out_size, void* d_ws, size_t ws_size,
                              hipStream_t stream) {
    const float* f_atoms = (const float*)d_in[0];
    const float* f_bonds = (const float*)d_in[1];
    const float* W_i     = (const float*)d_in[2];
    const float* W_m     = (const float*)d_in[3];
    const float* W_a     = (const float*)d_in[4];
    const float* b_a     = (const float*)d_in[5];
    const int* a2b       = (const int*)d_in[6];
    const int* b2a       = (const int*)d_in[7];
    const int* b2revb    = (const int*)d_in[8];
    const int* mol_index = (const int*)d_in[9];
    float* out = (float*)d_out;

    const size_t SZ_BH2 = (size_t)NB * H * 2;   // 128 MB bf16 message buf
    const size_t SZ_AG2 = (size_t)NA * H * 2;   // 32 MB bf16 agg
    const size_t SZ_WPM = 32 * 256 * 16;
    const size_t SZ_WPI = 20 * 256 * 16;
    const size_t SZ_WPA = 52 * 256 * 16;
    const size_t NEEDED = 3 * SZ_BH2 + SZ_AG2 + SZ_WPM + SZ_WPI + SZ_WPA;  // ~416 MB
    if (ws_size < NEEDED) return;  // diagnostic guard

    char* ws = (char*)d_ws;
    u32* inp    = (u32*)(ws);
    u32* msg1   = (u32*)(ws + SZ_BH2);
    u32* msg2   = (u32*)(ws + 2 * SZ_BH2);
    u32* aggb   = (u32*)(ws + 3 * SZ_BH2);
    uint4* WpM  = (uint4*)(ws + 3 * SZ_BH2 + SZ_AG2);
    uint4* WpI  = (uint4*)(ws + 3 * SZ_BH2 + SZ_AG2 + SZ_WPM);
    uint4* WpA  = (uint4*)(ws + 3 * SZ_BH2 + SZ_AG2 + SZ_WPM + SZ_WPI);
    u32* athb   = msg1;  // alias msg1 (dead by K4)

    // one-time weight packs
    k_pack_w<<<32, 256, 0, stream>>>(W_m, WpM, 256);
    k_pack_w<<<20, 256, 0, stream>>>(W_i, WpI, BF);
    k_pack_wa<<<52, 256, 0, stream>>>(W_a, WpA);

    // inp = f_bonds @ W_i (pre-activation, bf16); message0 = relu(inp) virtual
    k_gemm_wi<<<NB / 32, 256, 0, stream>>>(f_bonds, WpI, inp);

    // step 1
    k_agg<true><<<NA / 8, 256, 0, stream>>>(inp, a2b, aggb);
    k_msg_update<true><<<NB / 64, 256, 0, stream>>>(inp, aggb, inp, b2a, b2revb, WpM, msg1);

    // step 2
    k_agg<false><<<NA / 8, 256, 0, stream>>>(msg1, a2b, aggb);
    k_msg_update<false><<<NB / 64, 256, 0, stream>>>(inp, aggb, msg1, b2a, b2revb, WpM, msg2);

    // fused atom aggregation + W_a + relu
    k_atomh<<<NA / 64, 256, 0, stream>>>(f_atoms, msg2, a2b, WpA, b_a, athb);

    // per-molecule mean readout
    k_readout<<<NM, 256, 0, stream>>>((const u32*)athb, mol_index, out);
}